// Round 1
// 395.493 us; speedup vs baseline: 1.0358x; 1.0358x over previous
//
#include <hip/hip_runtime.h>

#define S_LEN 4096
#define HID   2048
#define NHQ   8
#define NKV   4
#define DHEAD 256
#define WIN   1024

typedef __attribute__((ext_vector_type(4))) float     floatx4;
typedef __attribute__((ext_vector_type(8))) _Float16  halfx8;
typedef __attribute__((ext_vector_type(8))) __bf16    bf16x8;

__device__ __forceinline__ unsigned short f2h(float f){
  union { _Float16 h; unsigned short u; } cv; cv.h = (_Float16)f; return cv.u;
}
__device__ __forceinline__ float h2f(unsigned short u){
  union { unsigned short u; _Float16 h; } cv; cv.u = u; return (float)cv.h;
}
__device__ __forceinline__ unsigned short f2bf(float f){
  unsigned int u = __float_as_uint(f);
  u += 0x7FFFu + ((u >> 16) & 1u);           // RNE
  return (unsigned short)(u >> 16);
}

__device__ __forceinline__ void gld_lds16(const void* g, void* l){
  __builtin_amdgcn_global_load_lds((const __attribute__((address_space(1))) void*)g,
                                   (__attribute__((address_space(3))) void*)l, 16, 0, 0);
}

// ---------------- merged converts (all fp32 -> fp16) ----------------
__global__ __launch_bounds__(256) void cvt_all(const float* __restrict__ hs,
                                               const float* __restrict__ Wq,
                                               const float* __restrict__ Wk,
                                               const float* __restrict__ Wv,
                                               const float* __restrict__ Wo,
                                               unsigned short* __restrict__ h_h,
                                               unsigned short* __restrict__ w_qkv,
                                               unsigned short* __restrict__ wo){
  int bid = blockIdx.x;
  const float* src;
  unsigned short* dst;
  size_t i;
  if (bid < 8192){
    i = ((size_t)bid * 256 + threadIdx.x) * 4;
    src = hs + i; dst = h_h + i;
  } else if (bid < 16384){
    i = ((size_t)(bid - 8192) * 256 + threadIdx.x) * 4;
    int row = (int)(i >> 11), col = (int)(i & 2047);
    src = ((row < 2048) ? (Wq + ((size_t)row << 11))
         : (row < 3072) ? (Wk + ((size_t)(row - 2048) << 11))
                        : (Wv + ((size_t)(row - 3072) << 11))) + col;
    dst = w_qkv + i;
  } else {
    i = ((size_t)(bid - 16384) * 256 + threadIdx.x) * 4;
    src = Wo + i; dst = wo + i;
  }
  float4 v = *(const float4*)src;
  *(ushort4*)dst = make_ushort4(f2h(v.x), f2h(v.y), f2h(v.z), f2h(v.w));
}

// ---------------- fp16 NT GEMM: C = A[M,K] * B[N,K]^T ----------------
template<int OUT_F32>
__global__ __launch_bounds__(256, 2) void gemm_ht(const unsigned short* __restrict__ A,
                                                  const unsigned short* __restrict__ B,
                                                  void* __restrict__ Cv,
                                                  int ldC, int K){
  __shared__ __align__(16) unsigned short As[128 * 32];
  __shared__ __align__(16) unsigned short Bs[128 * 32];
  const int t = threadIdx.x, w = t >> 6, lane = t & 63;
  const int quad = lane >> 4, l15 = lane & 15;
  const int l2 = lane >> 2, g8 = (lane & 3) * 8;
  const int wm = w >> 1, wn = w & 1;
  const int bm0 = blockIdx.y * 128, bn0 = blockIdx.x * 128;

  const floatx4 zf = {0.f, 0.f, 0.f, 0.f};
  floatx4 acc[4][4];
#pragma unroll
  for (int mi = 0; mi < 4; ++mi)
#pragma unroll
    for (int ni = 0; ni < 4; ++ni) acc[mi][ni] = zf;

  for (int k0 = 0; k0 < K; k0 += 32){
#pragma unroll
    for (int j = 0; j < 2; ++j){
      int ch  = j * 4 + w;
      int row = ch * 16 + l2;
      gld_lds16(A + (size_t)(bm0 + row) * K + k0 + g8, &As[ch * 512]);
      gld_lds16(B + (size_t)(bn0 + row) * K + k0 + g8, &Bs[ch * 512]);
    }
    __syncthreads();
    halfx8 af[4], bf[4];
#pragma unroll
    for (int mi = 0; mi < 4; ++mi) af[mi] = *(const halfx8*)&As[(wm*64 + mi*16 + l15)*32 + quad*8];
#pragma unroll
    for (int ni = 0; ni < 4; ++ni) bf[ni] = *(const halfx8*)&Bs[(wn*64 + ni*16 + l15)*32 + quad*8];
#pragma unroll
    for (int mi = 0; mi < 4; ++mi)
#pragma unroll
      for (int ni = 0; ni < 4; ++ni)
        acc[mi][ni] = __builtin_amdgcn_mfma_f32_16x16x32_f16(af[mi], bf[ni], acc[mi][ni], 0, 0, 0);
    __syncthreads();
  }
#pragma unroll
  for (int mi = 0; mi < 4; ++mi)
#pragma unroll
    for (int ni = 0; ni < 4; ++ni)
#pragma unroll
      for (int r = 0; r < 4; ++r){
        int m = bm0 + wm*64 + mi*16 + quad*4 + r;
        int n = bn0 + wn*64 + ni*16 + l15;
        float v = acc[mi][ni][r];
        if (OUT_F32) ((float*)Cv)[(size_t)m * ldC + n] = v;
        else         ((unsigned short*)Cv)[(size_t)m * ldC + n] = f2h(v);
      }
}

// ---------------- RMSNorm + RoPE post-process (fp16 in; Q/K fp16 out, V bf16 out) ----------------
__global__ __launch_bounds__(256) void qkv_post(const unsigned short* __restrict__ qkvh,
                                                const float* __restrict__ cosb,
                                                const float* __restrict__ sinb,
                                                const float* __restrict__ qnw,
                                                const float* __restrict__ knw,
                                                unsigned short* __restrict__ Qf,
                                                unsigned short* __restrict__ Kf,
                                                unsigned short* __restrict__ Vf){
  int gw   = blockIdx.x * 4 + (threadIdx.x >> 6);
  int lane = threadIdx.x & 63;
  int hh = gw & 15, s = gw >> 4;
  int colbase = (hh < 8) ? hh * 256 : (hh < 12 ? 2048 + (hh - 8) * 256 : 3072 + (hh - 12) * 256);

  ushort4 raw = *(const ushort4*)(qkvh + (size_t)s * 4096 + colbase + lane * 4);
  float x0 = h2f(raw.x), x1 = h2f(raw.y), x2 = h2f(raw.z), x3 = h2f(raw.w);
  float ss = x0*x0 + x1*x1 + x2*x2 + x3*x3;
#pragma unroll
  for (int off = 32; off; off >>= 1) ss += __shfl_xor(ss, off);
  float inv = rsqrtf(ss * (1.0f / 256.0f) + 1e-6f);

  if (hh < 12){
    const float* wp = (hh < 8) ? qnw : knw;
    float4 wv = *(const float4*)(wp + lane * 4);
    float y[4] = { x0*inv*wv.x, x1*inv*wv.y, x2*inv*wv.z, x3*inv*wv.w };
    float4 cv = *(const float4*)(cosb + (size_t)s * 256 + lane * 4);
    float4 sv = *(const float4*)(sinb + (size_t)s * 256 + lane * 4);
    float cj[4] = {cv.x, cv.y, cv.z, cv.w};
    float sj[4] = {sv.x, sv.y, sv.z, sv.w};
    unsigned short oh[4];
#pragma unroll
    for (int j = 0; j < 4; ++j){
      float oth = __shfl_xor(y[j], 32);          // element d +/- 128
      float rot = (lane < 32) ? -oth : oth;      // rot = [-x2, x1]
      oh[j] = f2h(y[j] * cj[j] + rot * sj[j]);
    }
    ushort4 r = make_ushort4(oh[0], oh[1], oh[2], oh[3]);
    if (hh < 8) *(ushort4*)(Qf + (size_t)(hh       * S_LEN + s) * DHEAD + lane * 4) = r;
    else        *(ushort4*)(Kf + (size_t)((hh - 8) * S_LEN + s) * DHEAD + lane * 4) = r;
  } else {
    // V in bf16 (PV matmul runs bf16 MFMA; bf16 exponent range needed by fixed-ref softmax P)
    ushort4 r = make_ushort4(f2bf(x0*inv), f2bf(x1*inv), f2bf(x2*inv), f2bf(x3*inv));
    *(ushort4*)(Vf + (size_t)((hh - 12) * S_LEN + s) * DHEAD + lane * 4) = r;
  }
}

// ---------------- V transpose: [kv][s][256] -> [kv][d][4096] (dtype-agnostic u16) ----------------
__global__ __launch_bounds__(256) void transpose_v(const unsigned short* __restrict__ v,
                                                   unsigned short* __restrict__ vt){
  __shared__ unsigned short tile[64][68];
  int kv = blockIdx.z, d0 = blockIdx.x * 64, s0 = blockIdx.y * 64;
  int t = threadIdx.x;
  int r = t >> 4, c4 = (t & 15) * 4;
#pragma unroll
  for (int i = 0; i < 4; ++i){
    int row = r + i * 16;
    ushort4 xx = *(const ushort4*)(v + (size_t)(kv * S_LEN + s0 + row) * DHEAD + d0 + c4);
    tile[row][c4] = xx.x; tile[row][c4+1] = xx.y; tile[row][c4+2] = xx.z; tile[row][c4+3] = xx.w;
  }
  __syncthreads();
#pragma unroll
  for (int i = 0; i < 4; ++i){
    int dr = r + i * 16;
    ushort4 yy = make_ushort4(tile[c4][dr], tile[c4+1][dr], tile[c4+2][dr], tile[c4+3][dr]);
    *(ushort4*)(vt + (size_t)(kv * DHEAD + d0 + dr) * S_LEN + s0 + c4) = yy;
  }
}

// ---------------- sliding-window softcapped flash attention ----------------
// v6 changes vs v5:
//  * T2 XOR-swizzle on Ks/Vts: both tiles are [row][32 u16] (64B rows); the
//    b128 fragment reads at row*64+quad*16 were ~8-way bank-conflicted
//    (8.5M SQ_LDS_BANK_CONFLICT). global_load_lds forces a linear LDS dest,
//    so the 16B col-slot is swizzled on the GLOBAL source (slot ^= (row>>1)&3)
//    and the identical involution is applied on the read index (rule #21).
//    Verified by enumeration: 64-lane b128 read now hits each bank-slot
//    exactly 2x (free).
//  * Pb row stride 48 -> 40 elements (80B): read (l15*80+quad*16) and write
//    patterns both become conflict-free (96B stride was 4-way).
//  * softcap+exp in exp2/rcp form: p = exp(20-100/(e^{0.04v}+1))
//      e = exp2(v*0.04*log2e); t = rcp(e+1); p = exp2(fma(t,-100*log2e, 20*log2e))
//    replaces 2x __expf + full-precision f32 divide (~10 instr) per element.
//  * XCD-affinity block remap (T1): 1-D grid, h = bid&7 -> each XCD keeps one
//    head's K/V (4MB ~= its L2) instead of streaming all 16MB.
//  * s_setprio(1) around both MFMA clusters (T5).
// Numerics: rcp/exp2 are ~1ulp vs the previous native exp + div; bf16-P
// rounding still dominates error. Fixed-reference softmax unchanged.
__global__ __launch_bounds__(256, 2) void attn_win(const unsigned short* __restrict__ Qg,
                                                   const unsigned short* __restrict__ Kg,
                                                   const unsigned short* __restrict__ Vt,
                                                   unsigned short* __restrict__ Og){
  __shared__ __align__(16) unsigned short Ks[2][8 * 32 * 32];   // 2x16 KB fp16
  __shared__ __align__(16) unsigned short Vts[2][256 * 32];     // 2x16 KB bf16
  __shared__ __align__(16) unsigned short Pb[4][16 * 40];       //  5 KB bf16

  const int bid = blockIdx.x;
  const int h = bid & 7, kv = h >> 1;          // XCD-affine: head = bid % 8
  const int q0 = (bid >> 3) * 64;
  const int t = threadIdx.x, w = t >> 6, lane = t & 63;
  const int quad = lane >> 4, l15 = lane & 15;
  const int l2 = lane >> 2;
  // swizzled 16B col-slot for staging (global source side): slot = (lane&3) ^ ((row>>1)&3)
  // where row's bits1-2 come from l2 for both K (krow=(ch&1)*16+l2) and V (drow=ch*16+l2)
  const int gsw = (((lane & 3) ^ ((l2 >> 1) & 3)) << 3);
  // swizzled 16B col-slot for fragment reads: rows are nt*16+l15 / dt*16+l15,
  // so (row>>1)&3 == (l15>>1)&3 — constant per lane
  const int qsw = ((quad ^ ((l15 >> 1) & 3)) << 3);
  const int qw0 = q0 + w * 16;

  halfx8 qf[8];
#pragma unroll
  for (int c = 0; c < 8; ++c)
    qf[c] = *(const halfx8*)(Qg + (size_t)(h * S_LEN + qw0 + l15) * DHEAD + c*32 + quad*8);

  const floatx4 zf = {0.f, 0.f, 0.f, 0.f};
  floatx4 oacc[16];
#pragma unroll
  for (int dt = 0; dt < 16; ++dt) oacc[dt] = zf;
  float l_part[4] = {0.f, 0.f, 0.f, 0.f};

  int kt_lo = q0 / 32 - 32; if (kt_lo < 0) kt_lo = 0;
  int kt_hi = q0 / 32 + 1;

  const size_t kbase = (size_t)kv * S_LEN * DHEAD;
  const size_t vbase = (size_t)kv * DHEAD * S_LEN;

#define STAGE(KT, B)                                                              \
  {                                                                               \
    const int key0_ = (KT) * 32;                                                  \
    _Pragma("unroll")                                                             \
    for (int j = 0; j < 4; ++j){                                                  \
      int ch = j * 4 + w;                                                         \
      int krow = (ch & 1) * 16 + l2;                                              \
      int cb = ch >> 1;                                                           \
      gld_lds16(Kg + kbase + (size_t)(key0_ + krow) * DHEAD + cb * 32 + gsw,      \
                &Ks[B][ch * 512]);                                                \
      int drow = ch * 16 + l2;                                                    \
      gld_lds16(Vt + vbase + (size_t)drow * S_LEN + key0_ + gsw,                  \
                &Vts[B][ch * 512]);                                               \
    }                                                                             \
  }

  STAGE(kt_lo, 0);

  for (int kt = kt_lo; kt <= kt_hi; ++kt){
    const int cur = (kt - kt_lo) & 1;
    __syncthreads();                 // drains vmcnt: buf[cur] ready; prev compute done
    if (kt < kt_hi) STAGE(kt + 1, cur ^ 1);

    const int key0 = kt * 32;
    if (key0 <= qw0 + 15 && key0 + 31 >= qw0 - (WIN - 1)){
      // QK^T: 16 MFMA (fp16)
      floatx4 sc[2];
      sc[0] = zf; sc[1] = zf;
      __builtin_amdgcn_s_setprio(1);
#pragma unroll
      for (int c = 0; c < 8; ++c){
#pragma unroll
        for (int nt = 0; nt < 2; ++nt){
          halfx8 kf = *(const halfx8*)&Ks[cur][c * 1024 + (nt*16 + l15) * 32 + qsw];
          sc[nt] = __builtin_amdgcn_mfma_f32_16x16x32_f16(qf[c], kf, sc[nt], 0, 0, 0);
        }
      }
      __builtin_amdgcn_s_setprio(0);
      const bool tfull = (key0 + 31 <= qw0) && (qw0 + 15 - key0 < WIN);
      // fused softcap+exp vs fixed reference 30, exp2/rcp form:
      //   s = 50 - 100/(e^{0.04v}+1);  p = exp(s-30)
#pragma unroll
      for (int nt = 0; nt < 2; ++nt)
#pragma unroll
        for (int r = 0; r < 4; ++r){
          float v = sc[nt][r];
          float e  = __builtin_amdgcn_exp2f(v * 0.0577078016f);           // e^{0.04v}
          float tt = __builtin_amdgcn_rcpf(e + 1.0f);                     // 1/(e+1)
          float p  = __builtin_amdgcn_exp2f(fmaf(tt, -144.26950408f, 28.8539008f));
          if (!tfull){
            int qi = qw0 + quad*4 + r;
            int ki = key0 + nt*16 + l15;
            p = ((ki <= qi) && (qi - ki < WIN)) ? p : 0.0f;
          }
          l_part[r] += p;
          Pb[w][(quad*4 + r) * 40 + nt*16 + l15] = f2bf(p);
        }
      // PV: 16 MFMA (bf16)
      bf16x8 pf = *(const bf16x8*)&Pb[w][l15 * 40 + quad * 8];
      __builtin_amdgcn_s_setprio(1);
#pragma unroll
      for (int dt = 0; dt < 16; ++dt){
        bf16x8 vf = *(const bf16x8*)&Vts[cur][(dt*16 + l15) * 32 + qsw];
        oacc[dt] = __builtin_amdgcn_mfma_f32_16x16x32_bf16(pf, vf, oacc[dt], 0, 0, 0);
      }
      __builtin_amdgcn_s_setprio(0);
    }
  }
#undef STAGE

  // epilogue: reduce l across the 16-lane row groups, normalize, store fp16
#pragma unroll
  for (int r = 0; r < 4; ++r){
    float l = l_part[r];
    l += __shfl_xor(l, 1);
    l += __shfl_xor(l, 2);
    l += __shfl_xor(l, 4);
    l += __shfl_xor(l, 8);
    float rl = 1.0f / l;
    int srow = qw0 + quad*4 + r;
#pragma unroll
    for (int dt = 0; dt < 16; ++dt)
      Og[(size_t)srow * (NHQ * DHEAD) + h * DHEAD + dt*16 + l15] = f2h(oacc[dt][r] * rl);
  }
}

// ---------------- launch ----------------
extern "C" void kernel_launch(void* const* d_in, const int* in_sizes, int n_in,
                              void* d_out, int out_size, void* d_ws, size_t ws_size,
                              hipStream_t stream){
  const float* hs   = (const float*)d_in[0];
  const float* cosb = (const float*)d_in[1];
  const float* sinb = (const float*)d_in[2];
  // d_in[3] = attention_mask: structure known (0 <= q-k < 1024), never read
  const float* Wq   = (const float*)d_in[4];
  const float* Wk   = (const float*)d_in[5];
  const float* Wv   = (const float*)d_in[6];
  const float* Wo   = (const float*)d_in[7];
  const float* qnw  = (const float*)d_in[8];
  const float* knw  = (const float*)d_in[9];
  float* out = (float*)d_out;

  const size_t MB = 1024ull * 1024ull;
  char* ws = (char*)d_ws;
  unsigned short* h_h   = (unsigned short*)(ws);             // 16 MB [4096][2048] fp16
  unsigned short* w_qkv = (unsigned short*)(ws + 16 * MB);   // 16 MB [4096][2048]
  unsigned short* wo    = (unsigned short*)(ws + 32 * MB);   //  8 MB [2048][2048]
  unsigned short* qkvh  = (unsigned short*)(ws + 40 * MB);   // 32 MB [4096][4096] fp16
  // after QKV GEMM, h_h/w_qkv dead -> Q/K/V live there
  unsigned short* Qf    = (unsigned short*)(ws);             // 16 MB [8][4096][256] fp16
  unsigned short* Kf    = (unsigned short*)(ws + 16 * MB);   //  8 MB [4][4096][256] fp16
  unsigned short* Vf    = (unsigned short*)(ws + 24 * MB);   //  8 MB [4][4096][256] bf16
  // after qkv_post, qkvh dead -> Vt + attention output live there
  unsigned short* vt    = (unsigned short*)(ws + 40 * MB);   //  8 MB [4][256][4096] bf16
  unsigned short* ob    = (unsigned short*)(ws + 48 * MB);   // 16 MB [4096][2048] fp16

  cvt_all<<<20480, 256, 0, stream>>>(hs, Wq, Wk, Wv, Wo, h_h, w_qkv, wo);

  gemm_ht<0><<<dim3(32, 32), 256, 0, stream>>>(h_h, w_qkv, qkvh, 4096, 2048);

  qkv_post<<<16384, 256, 0, stream>>>(qkvh, cosb, sinb, qnw, knw, Qf, Kf, Vf);
  transpose_v<<<dim3(4, 64, 4), 256, 0, stream>>>(Vf, vt);

  attn_win<<<512, 256, 0, stream>>>(Qf, Kf, vt, ob);

  gemm_ht<1><<<dim3(16, 32), 256, 0, stream>>>(ob, wo, out, 2048, 2048);
}

// Round 2
// 387.911 us; speedup vs baseline: 1.0560x; 1.0195x over previous
//
#include <hip/hip_runtime.h>

#define S_LEN 4096
#define HID   2048
#define NHQ   8
#define NKV   4
#define DHEAD 256
#define WIN   1024

typedef __attribute__((ext_vector_type(4))) float     floatx4;
typedef __attribute__((ext_vector_type(8))) _Float16  halfx8;
typedef __attribute__((ext_vector_type(8))) __bf16    bf16x8;

__device__ __forceinline__ unsigned short f2h(float f){
  union { _Float16 h; unsigned short u; } cv; cv.h = (_Float16)f; return cv.u;
}
__device__ __forceinline__ float h2f(unsigned short u){
  union { unsigned short u; _Float16 h; } cv; cv.u = u; return (float)cv.h;
}
__device__ __forceinline__ unsigned short f2bf(float f){
  unsigned int u = __float_as_uint(f);
  u += 0x7FFFu + ((u >> 16) & 1u);           // RNE
  return (unsigned short)(u >> 16);
}

__device__ __forceinline__ void gld_lds16(const void* g, void* l){
  __builtin_amdgcn_global_load_lds((const __attribute__((address_space(1))) void*)g,
                                   (__attribute__((address_space(3))) void*)l, 16, 0, 0);
}

// ---------------- merged converts (all fp32 -> fp16) ----------------
__global__ __launch_bounds__(256) void cvt_all(const float* __restrict__ hs,
                                               const float* __restrict__ Wq,
                                               const float* __restrict__ Wk,
                                               const float* __restrict__ Wv,
                                               const float* __restrict__ Wo,
                                               unsigned short* __restrict__ h_h,
                                               unsigned short* __restrict__ w_qkv,
                                               unsigned short* __restrict__ wo){
  int bid = blockIdx.x;
  const float* src;
  unsigned short* dst;
  size_t i;
  if (bid < 8192){
    i = ((size_t)bid * 256 + threadIdx.x) * 4;
    src = hs + i; dst = h_h + i;
  } else if (bid < 16384){
    i = ((size_t)(bid - 8192) * 256 + threadIdx.x) * 4;
    int row = (int)(i >> 11), col = (int)(i & 2047);
    src = ((row < 2048) ? (Wq + ((size_t)row << 11))
         : (row < 3072) ? (Wk + ((size_t)(row - 2048) << 11))
                        : (Wv + ((size_t)(row - 3072) << 11))) + col;
    dst = w_qkv + i;
  } else {
    i = ((size_t)(bid - 16384) * 256 + threadIdx.x) * 4;
    src = Wo + i; dst = wo + i;
  }
  float4 v = *(const float4*)src;
  *(ushort4*)dst = make_ushort4(f2h(v.x), f2h(v.y), f2h(v.z), f2h(v.w));
}

// ---------------- 256x256 multi-phase counted-vmcnt fp16 NT GEMM ----------------
// C[M,N] = A[M,K] * B[N,K]^T, fp16 out. Requires M%256==0, N%256==0, K%32==0, K/32>=4.
// Structure (T3+T4 template, derived-safe waits):
//  * 512 thr = 8 waves (2M x 4N); per-wave 128x64 out; acc[8][4] floatx4.
//  * LDS: 4-slot ring, slot = {A 256x32, B 256x32} fp16 = 32 KB; 128 KB total.
//    4-deep ring makes counted vmcnt legal: computing tile t, t+1/t+2 landed or
//    in flight, t+3 being issued. Per-tile wait vmcnt(8) (= 2 tiles x 4 loads
//    still in flight), NEVER 0 in the main loop; tail derives 8->4->0.
//  * 2 phases/K-tile, 16 MFMA each:
//      {ds_read frags; issue 2 gld_lds; s_barrier; lgkmcnt(0); sched_barrier;
//       setprio(1); 16 MFMA; setprio(0); [vmcnt at phase B]; s_barrier}
//    Post-MFMA barrier = correctness gate for slot reuse (every wave's LDS
//    reads drained by its pre-MFMA lgkmcnt(0) before the barrier; only after
//    it may loads targeting that slot be issued). Raw s_barrier only --
//    __syncthreads() would emit vmcnt(0) and kill the pipeline.
//  * T2 swizzle: 16B col-slot ^= ((row>>1)&3), applied on the GLOBAL source
//    (gld_lds dest must stay linear) and identically on the fragment read.
//  * T1: 1-D grid, bijective XCD swizzle (nwg=256 % 8 == 0).
// Accumulation order identical to the old 128^2 kernel (same MFMA per 32-K
// step, sequential K) -> numerics unchanged.
__global__ __launch_bounds__(512, 2) void gemm_qkv(const unsigned short* __restrict__ A,
                                                   const unsigned short* __restrict__ B,
                                                   unsigned short* __restrict__ C,
                                                   int ldC, int K){
  __shared__ __align__(16) unsigned short As[4][256 * 32];
  __shared__ __align__(16) unsigned short Bs[4][256 * 32];
  const int T = K >> 5;                        // 32-K tiles
  const int t0 = threadIdx.x;                  // 0..511
  const int w = t0 >> 6, lane = t0 & 63;
  const int wm = w >> 2, wn = w & 3;
  const int quad = lane >> 4, l15 = lane & 15;
  const int qsw8 = ((quad ^ ((l15 >> 1) & 3)) << 3);   // swizzled read slot (elems)

  // stage mapping: thread t0 -> row t0>>2 (of a 128-row half), 16B slot t0&3
  const int srow   = t0 >> 2;
  const int swcol8 = (((t0 & 3) ^ ((t0 >> 3) & 3)) << 3);  // swizzled global slot
  const int sldst  = srow * 32 + ((t0 & 3) << 3);          // linear LDS dest (elems)

  // XCD-bijective swizzle over the 1-D 256-block grid (16x16 tiles)
  const int bid = blockIdx.x;
  const int wg = (bid & 7) * 32 + (bid >> 3);
  const int bm0 = (wg >> 4) * 256, bn0 = (wg & 15) * 256;

  const unsigned short* a0 = A + (size_t)(bm0 +       srow) * K + swcol8;
  const unsigned short* a1 = A + (size_t)(bm0 + 128 + srow) * K + swcol8;
  const unsigned short* b0 = B + (size_t)(bn0 +       srow) * K + swcol8;
  const unsigned short* b1 = B + (size_t)(bn0 + 128 + srow) * K + swcol8;

#define STA(U) { const int sl_ = (U) & 3;                                   \
    gld_lds16(a0 + (size_t)(U) * 32, &As[sl_][sldst]);                      \
    gld_lds16(a1 + (size_t)(U) * 32, &As[sl_][4096 + sldst]); }
#define STB(U) { const int sl_ = (U) & 3;                                   \
    gld_lds16(b0 + (size_t)(U) * 32, &Bs[sl_][sldst]);                      \
    gld_lds16(b1 + (size_t)(U) * 32, &Bs[sl_][4096 + sldst]); }

  // prologue: issue tiles 0,1,2 (12 loads/thread); wait tile0 (keep 8 in flight)
  STA(0) STB(0) STA(1) STB(1) STA(2) STB(2)
  asm volatile("s_waitcnt vmcnt(8)" ::: "memory");
  __builtin_amdgcn_s_barrier();
  __builtin_amdgcn_sched_barrier(0);

  const floatx4 zf = {0.f, 0.f, 0.f, 0.f};
  floatx4 acc[8][4];
#pragma unroll
  for (int mi = 0; mi < 8; ++mi)
#pragma unroll
    for (int ni = 0; ni < 4; ++ni) acc[mi][ni] = zf;

  const int arow = wm * 128 + l15;   // + mi*16 (+64 in phase B)
  const int brow = wn * 64  + l15;   // + ni*16

  for (int t = 0; t < T; ++t){
    const int s = t & 3;
    const unsigned short* Ap = &As[s][0];
    const unsigned short* Bp = &Bs[s][0];
    halfx8 af[4], bf[4];

    // ---------- phase A: m-frags 0-3 x n-frags 0-3 ----------
#pragma unroll
    for (int mi = 0; mi < 4; ++mi) af[mi] = *(const halfx8*)&Ap[(arow + mi*16) * 32 + qsw8];
#pragma unroll
    for (int ni = 0; ni < 4; ++ni) bf[ni] = *(const halfx8*)&Bp[(brow + ni*16) * 32 + qsw8];
    if (t + 3 < T) STA(t + 3)
    __builtin_amdgcn_s_barrier();
    asm volatile("s_waitcnt lgkmcnt(0)" ::: "memory");
    __builtin_amdgcn_sched_barrier(0);
    __builtin_amdgcn_s_setprio(1);
#pragma unroll
    for (int mi = 0; mi < 4; ++mi)
#pragma unroll
      for (int ni = 0; ni < 4; ++ni)
        acc[mi][ni] = __builtin_amdgcn_mfma_f32_16x16x32_f16(af[mi], bf[ni], acc[mi][ni], 0, 0, 0);
    __builtin_amdgcn_s_setprio(0);
    __builtin_amdgcn_s_barrier();
    __builtin_amdgcn_sched_barrier(0);

    // ---------- phase B: m-frags 4-7 x n-frags 0-3 ----------
#pragma unroll
    for (int mi = 0; mi < 4; ++mi) af[mi] = *(const halfx8*)&Ap[(arow + 64 + mi*16) * 32 + qsw8];
    if (t + 3 < T) STB(t + 3)
    __builtin_amdgcn_s_barrier();
    asm volatile("s_waitcnt lgkmcnt(0)" ::: "memory");
    __builtin_amdgcn_sched_barrier(0);
    __builtin_amdgcn_s_setprio(1);
#pragma unroll
    for (int mi = 0; mi < 4; ++mi)
#pragma unroll
      for (int ni = 0; ni < 4; ++ni)
        acc[4 + mi][ni] = __builtin_amdgcn_mfma_f32_16x16x32_f16(af[mi], bf[ni], acc[4 + mi][ni], 0, 0, 0);
    __builtin_amdgcn_s_setprio(0);
    // counted drain: ensure tile t+1 landed; keep the rest in flight
    if (t < T - 3)       { asm volatile("s_waitcnt vmcnt(8)" ::: "memory"); }
    else if (t == T - 3) { asm volatile("s_waitcnt vmcnt(4)" ::: "memory"); }
    else if (t == T - 2) { asm volatile("s_waitcnt vmcnt(0)" ::: "memory"); }
    __builtin_amdgcn_s_barrier();
    __builtin_amdgcn_sched_barrier(0);
  }
#undef STA
#undef STB

  // epilogue: store fp16
#pragma unroll
  for (int mi = 0; mi < 8; ++mi)
#pragma unroll
    for (int ni = 0; ni < 4; ++ni)
#pragma unroll
      for (int r = 0; r < 4; ++r){
        int m = bm0 + wm*128 + (mi >> 2)*64 + (mi & 3)*16 + quad*4 + r;
        int n = bn0 + wn*64 + ni*16 + l15;
        C[(size_t)m * ldC + n] = f2h(acc[mi][ni][r]);
      }
}

// ---------------- fp16 NT GEMM: C = A[M,K] * B[N,K]^T (128^2, out-proj) ----------------
template<int OUT_F32>
__global__ __launch_bounds__(256, 2) void gemm_ht(const unsigned short* __restrict__ A,
                                                  const unsigned short* __restrict__ B,
                                                  void* __restrict__ Cv,
                                                  int ldC, int K){
  __shared__ __align__(16) unsigned short As[128 * 32];
  __shared__ __align__(16) unsigned short Bs[128 * 32];
  const int t = threadIdx.x, w = t >> 6, lane = t & 63;
  const int quad = lane >> 4, l15 = lane & 15;
  const int l2 = lane >> 2, g8 = (lane & 3) * 8;
  const int wm = w >> 1, wn = w & 1;
  const int bm0 = blockIdx.y * 128, bn0 = blockIdx.x * 128;

  const floatx4 zf = {0.f, 0.f, 0.f, 0.f};
  floatx4 acc[4][4];
#pragma unroll
  for (int mi = 0; mi < 4; ++mi)
#pragma unroll
    for (int ni = 0; ni < 4; ++ni) acc[mi][ni] = zf;

  for (int k0 = 0; k0 < K; k0 += 32){
#pragma unroll
    for (int j = 0; j < 2; ++j){
      int ch  = j * 4 + w;
      int row = ch * 16 + l2;
      gld_lds16(A + (size_t)(bm0 + row) * K + k0 + g8, &As[ch * 512]);
      gld_lds16(B + (size_t)(bn0 + row) * K + k0 + g8, &Bs[ch * 512]);
    }
    __syncthreads();
    halfx8 af[4], bf[4];
#pragma unroll
    for (int mi = 0; mi < 4; ++mi) af[mi] = *(const halfx8*)&As[(wm*64 + mi*16 + l15)*32 + quad*8];
#pragma unroll
    for (int ni = 0; ni < 4; ++ni) bf[ni] = *(const halfx8*)&Bs[(wn*64 + ni*16 + l15)*32 + quad*8];
#pragma unroll
    for (int mi = 0; mi < 4; ++mi)
#pragma unroll
      for (int ni = 0; ni < 4; ++ni)
        acc[mi][ni] = __builtin_amdgcn_mfma_f32_16x16x32_f16(af[mi], bf[ni], acc[mi][ni], 0, 0, 0);
    __syncthreads();
  }
#pragma unroll
  for (int mi = 0; mi < 4; ++mi)
#pragma unroll
    for (int ni = 0; ni < 4; ++ni)
#pragma unroll
      for (int r = 0; r < 4; ++r){
        int m = bm0 + wm*64 + mi*16 + quad*4 + r;
        int n = bn0 + wn*64 + ni*16 + l15;
        float v = acc[mi][ni][r];
        if (OUT_F32) ((float*)Cv)[(size_t)m * ldC + n] = v;
        else         ((unsigned short*)Cv)[(size_t)m * ldC + n] = f2h(v);
      }
}

// ---------------- RMSNorm + RoPE post-process (fp16 in; Q/K fp16 out, V bf16 out) ----------------
__global__ __launch_bounds__(256) void qkv_post(const unsigned short* __restrict__ qkvh,
                                                const float* __restrict__ cosb,
                                                const float* __restrict__ sinb,
                                                const float* __restrict__ qnw,
                                                const float* __restrict__ knw,
                                                unsigned short* __restrict__ Qf,
                                                unsigned short* __restrict__ Kf,
                                                unsigned short* __restrict__ Vf){
  int gw   = blockIdx.x * 4 + (threadIdx.x >> 6);
  int lane = threadIdx.x & 63;
  int hh = gw & 15, s = gw >> 4;
  int colbase = (hh < 8) ? hh * 256 : (hh < 12 ? 2048 + (hh - 8) * 256 : 3072 + (hh - 12) * 256);

  ushort4 raw = *(const ushort4*)(qkvh + (size_t)s * 4096 + colbase + lane * 4);
  float x0 = h2f(raw.x), x1 = h2f(raw.y), x2 = h2f(raw.z), x3 = h2f(raw.w);
  float ss = x0*x0 + x1*x1 + x2*x2 + x3*x3;
#pragma unroll
  for (int off = 32; off; off >>= 1) ss += __shfl_xor(ss, off);
  float inv = rsqrtf(ss * (1.0f / 256.0f) + 1e-6f);

  if (hh < 12){
    const float* wp = (hh < 8) ? qnw : knw;
    float4 wv = *(const float4*)(wp + lane * 4);
    float y[4] = { x0*inv*wv.x, x1*inv*wv.y, x2*inv*wv.z, x3*inv*wv.w };
    float4 cv = *(const float4*)(cosb + (size_t)s * 256 + lane * 4);
    float4 sv = *(const float4*)(sinb + (size_t)s * 256 + lane * 4);
    float cj[4] = {cv.x, cv.y, cv.z, cv.w};
    float sj[4] = {sv.x, sv.y, sv.z, sv.w};
    unsigned short oh[4];
#pragma unroll
    for (int j = 0; j < 4; ++j){
      float oth = __shfl_xor(y[j], 32);          // element d +/- 128
      float rot = (lane < 32) ? -oth : oth;      // rot = [-x2, x1]
      oh[j] = f2h(y[j] * cj[j] + rot * sj[j]);
    }
    ushort4 r = make_ushort4(oh[0], oh[1], oh[2], oh[3]);
    if (hh < 8) *(ushort4*)(Qf + (size_t)(hh       * S_LEN + s) * DHEAD + lane * 4) = r;
    else        *(ushort4*)(Kf + (size_t)((hh - 8) * S_LEN + s) * DHEAD + lane * 4) = r;
  } else {
    // V in bf16 (PV matmul runs bf16 MFMA; bf16 exponent range needed by fixed-ref softmax P)
    ushort4 r = make_ushort4(f2bf(x0*inv), f2bf(x1*inv), f2bf(x2*inv), f2bf(x3*inv));
    *(ushort4*)(Vf + (size_t)((hh - 12) * S_LEN + s) * DHEAD + lane * 4) = r;
  }
}

// ---------------- V transpose: [kv][s][256] -> [kv][d][4096] (dtype-agnostic u16) ----------------
__global__ __launch_bounds__(256) void transpose_v(const unsigned short* __restrict__ v,
                                                   unsigned short* __restrict__ vt){
  __shared__ unsigned short tile[64][68];
  int kv = blockIdx.z, d0 = blockIdx.x * 64, s0 = blockIdx.y * 64;
  int t = threadIdx.x;
  int r = t >> 4, c4 = (t & 15) * 4;
#pragma unroll
  for (int i = 0; i < 4; ++i){
    int row = r + i * 16;
    ushort4 xx = *(const ushort4*)(v + (size_t)(kv * S_LEN + s0 + row) * DHEAD + d0 + c4);
    tile[row][c4] = xx.x; tile[row][c4+1] = xx.y; tile[row][c4+2] = xx.z; tile[row][c4+3] = xx.w;
  }
  __syncthreads();
#pragma unroll
  for (int i = 0; i < 4; ++i){
    int dr = r + i * 16;
    ushort4 yy = make_ushort4(tile[c4][dr], tile[c4+1][dr], tile[c4+2][dr], tile[c4+3][dr]);
    *(ushort4*)(vt + (size_t)(kv * DHEAD + d0 + dr) * S_LEN + s0 + c4) = yy;
  }
}

// ---------------- sliding-window softcapped flash attention ----------------
// v6: T2 source-side XOR swizzle on Ks/Vts + Pb stride 40; exp2/rcp softcap;
// XCD-affine block remap; setprio around MFMA clusters. See round-1 notes.
__global__ __launch_bounds__(256, 2) void attn_win(const unsigned short* __restrict__ Qg,
                                                   const unsigned short* __restrict__ Kg,
                                                   const unsigned short* __restrict__ Vt,
                                                   unsigned short* __restrict__ Og){
  __shared__ __align__(16) unsigned short Ks[2][8 * 32 * 32];   // 2x16 KB fp16
  __shared__ __align__(16) unsigned short Vts[2][256 * 32];     // 2x16 KB bf16
  __shared__ __align__(16) unsigned short Pb[4][16 * 40];       //  5 KB bf16

  const int bid = blockIdx.x;
  const int h = bid & 7, kv = h >> 1;          // XCD-affine: head = bid % 8
  const int q0 = (bid >> 3) * 64;
  const int t = threadIdx.x, w = t >> 6, lane = t & 63;
  const int quad = lane >> 4, l15 = lane & 15;
  const int l2 = lane >> 2;
  const int gsw = (((lane & 3) ^ ((l2 >> 1) & 3)) << 3);
  const int qsw = ((quad ^ ((l15 >> 1) & 3)) << 3);
  const int qw0 = q0 + w * 16;

  halfx8 qf[8];
#pragma unroll
  for (int c = 0; c < 8; ++c)
    qf[c] = *(const halfx8*)(Qg + (size_t)(h * S_LEN + qw0 + l15) * DHEAD + c*32 + quad*8);

  const floatx4 zf = {0.f, 0.f, 0.f, 0.f};
  floatx4 oacc[16];
#pragma unroll
  for (int dt = 0; dt < 16; ++dt) oacc[dt] = zf;
  float l_part[4] = {0.f, 0.f, 0.f, 0.f};

  int kt_lo = q0 / 32 - 32; if (kt_lo < 0) kt_lo = 0;
  int kt_hi = q0 / 32 + 1;

  const size_t kbase = (size_t)kv * S_LEN * DHEAD;
  const size_t vbase = (size_t)kv * DHEAD * S_LEN;

#define STAGE(KT, B)                                                              \
  {                                                                               \
    const int key0_ = (KT) * 32;                                                  \
    _Pragma("unroll")                                                             \
    for (int j = 0; j < 4; ++j){                                                  \
      int ch = j * 4 + w;                                                         \
      int krow = (ch & 1) * 16 + l2;                                              \
      int cb = ch >> 1;                                                           \
      gld_lds16(Kg + kbase + (size_t)(key0_ + krow) * DHEAD + cb * 32 + gsw,      \
                &Ks[B][ch * 512]);                                                \
      int drow = ch * 16 + l2;                                                    \
      gld_lds16(Vt + vbase + (size_t)drow * S_LEN + key0_ + gsw,                  \
                &Vts[B][ch * 512]);                                               \
    }                                                                             \
  }

  STAGE(kt_lo, 0);

  for (int kt = kt_lo; kt <= kt_hi; ++kt){
    const int cur = (kt - kt_lo) & 1;
    __syncthreads();                 // drains vmcnt: buf[cur] ready; prev compute done
    if (kt < kt_hi) STAGE(kt + 1, cur ^ 1);

    const int key0 = kt * 32;
    if (key0 <= qw0 + 15 && key0 + 31 >= qw0 - (WIN - 1)){
      // QK^T: 16 MFMA (fp16)
      floatx4 sc[2];
      sc[0] = zf; sc[1] = zf;
      __builtin_amdgcn_s_setprio(1);
#pragma unroll
      for (int c = 0; c < 8; ++c){
#pragma unroll
        for (int nt = 0; nt < 2; ++nt){
          halfx8 kf = *(const halfx8*)&Ks[cur][c * 1024 + (nt*16 + l15) * 32 + qsw];
          sc[nt] = __builtin_amdgcn_mfma_f32_16x16x32_f16(qf[c], kf, sc[nt], 0, 0, 0);
        }
      }
      __builtin_amdgcn_s_setprio(0);
      const bool tfull = (key0 + 31 <= qw0) && (qw0 + 15 - key0 < WIN);
      // fused softcap+exp vs fixed reference 30, exp2/rcp form:
      //   s = 50 - 100/(e^{0.04v}+1);  p = exp(s-30)
#pragma unroll
      for (int nt = 0; nt < 2; ++nt)
#pragma unroll
        for (int r = 0; r < 4; ++r){
          float v = sc[nt][r];
          float e  = __builtin_amdgcn_exp2f(v * 0.0577078016f);           // e^{0.04v}
          float tt = __builtin_amdgcn_rcpf(e + 1.0f);                     // 1/(e+1)
          float p  = __builtin_amdgcn_exp2f(fmaf(tt, -144.26950408f, 28.8539008f));
          if (!tfull){
            int qi = qw0 + quad*4 + r;
            int ki = key0 + nt*16 + l15;
            p = ((ki <= qi) && (qi - ki < WIN)) ? p : 0.0f;
          }
          l_part[r] += p;
          Pb[w][(quad*4 + r) * 40 + nt*16 + l15] = f2bf(p);
        }
      // PV: 16 MFMA (bf16)
      bf16x8 pf = *(const bf16x8*)&Pb[w][l15 * 40 + quad * 8];
      __builtin_amdgcn_s_setprio(1);
#pragma unroll
      for (int dt = 0; dt < 16; ++dt){
        bf16x8 vf = *(const bf16x8*)&Vts[cur][(dt*16 + l15) * 32 + qsw];
        oacc[dt] = __builtin_amdgcn_mfma_f32_16x16x32_bf16(pf, vf, oacc[dt], 0, 0, 0);
      }
      __builtin_amdgcn_s_setprio(0);
    }
  }
#undef STAGE

  // epilogue: reduce l across the 16-lane row groups, normalize, store fp16
#pragma unroll
  for (int r = 0; r < 4; ++r){
    float l = l_part[r];
    l += __shfl_xor(l, 1);
    l += __shfl_xor(l, 2);
    l += __shfl_xor(l, 4);
    l += __shfl_xor(l, 8);
    float rl = 1.0f / l;
    int srow = qw0 + quad*4 + r;
#pragma unroll
    for (int dt = 0; dt < 16; ++dt)
      Og[(size_t)srow * (NHQ * DHEAD) + h * DHEAD + dt*16 + l15] = f2h(oacc[dt][r] * rl);
  }
}

// ---------------- launch ----------------
extern "C" void kernel_launch(void* const* d_in, const int* in_sizes, int n_in,
                              void* d_out, int out_size, void* d_ws, size_t ws_size,
                              hipStream_t stream){
  const float* hs   = (const float*)d_in[0];
  const float* cosb = (const float*)d_in[1];
  const float* sinb = (const float*)d_in[2];
  // d_in[3] = attention_mask: structure known (0 <= q-k < 1024), never read
  const float* Wq   = (const float*)d_in[4];
  const float* Wk   = (const float*)d_in[5];
  const float* Wv   = (const float*)d_in[6];
  const float* Wo   = (const float*)d_in[7];
  const float* qnw  = (const float*)d_in[8];
  const float* knw  = (const float*)d_in[9];
  float* out = (float*)d_out;

  const size_t MB = 1024ull * 1024ull;
  char* ws = (char*)d_ws;
  unsigned short* h_h   = (unsigned short*)(ws);             // 16 MB [4096][2048] fp16
  unsigned short* w_qkv = (unsigned short*)(ws + 16 * MB);   // 16 MB [4096][2048]
  unsigned short* wo    = (unsigned short*)(ws + 32 * MB);   //  8 MB [2048][2048]
  unsigned short* qkvh  = (unsigned short*)(ws + 40 * MB);   // 32 MB [4096][4096] fp16
  // after QKV GEMM, h_h/w_qkv dead -> Q/K/V live there
  unsigned short* Qf    = (unsigned short*)(ws);             // 16 MB [8][4096][256] fp16
  unsigned short* Kf    = (unsigned short*)(ws + 16 * MB);   //  8 MB [4][4096][256] fp16
  unsigned short* Vf    = (unsigned short*)(ws + 24 * MB);   //  8 MB [4][4096][256] bf16
  // after qkv_post, qkvh dead -> Vt + attention output live there
  unsigned short* vt    = (unsigned short*)(ws + 40 * MB);   //  8 MB [4][256][4096] bf16
  unsigned short* ob    = (unsigned short*)(ws + 48 * MB);   // 16 MB [4096][2048] fp16

  cvt_all<<<20480, 256, 0, stream>>>(hs, Wq, Wk, Wv, Wo, h_h, w_qkv, wo);

  gemm_qkv<<<256, 512, 0, stream>>>(h_h, w_qkv, qkvh, 4096, 2048);

  qkv_post<<<16384, 256, 0, stream>>>(qkvh, cosb, sinb, qnw, knw, Qf, Kf, Vf);
  transpose_v<<<dim3(4, 64, 4), 256, 0, stream>>>(Vf, vt);

  attn_win<<<512, 256, 0, stream>>>(Qf, Kf, vt, ob);

  gemm_ht<1><<<dim3(16, 32), 256, 0, stream>>>(ob, wo, out, 2048, 2048);
}